// Round 5
// baseline (443.007 us; speedup 1.0000x reference)
//
#include <hip/hip_runtime.h>
#include <stdint.h>

#define B_ 4
#define T_ 64
#define P_ 256
#define E_ 512
#define H_ 8
#define D_ 64
#define NF 1536
#define MCH 16384   // tokens per b-chunk (T_*P_)

typedef unsigned short u16;
typedef __attribute__((ext_vector_type(8))) __bf16 bf16x8;
typedef __attribute__((ext_vector_type(4))) float f32x4;

__device__ __forceinline__ u16 f2bf(float x) {
  union { float f; uint32_t u; } a; a.f = x;
  uint32_t u = a.u;
  uint32_t r = (u + 0x7FFFu + ((u >> 16) & 1u)) >> 16;
  return (u16)r;
}

__device__ __forceinline__ bf16x8 ld8(const u16* p) {
  union { uint4 u; bf16x8 b; } t;
  t.u = *reinterpret_cast<const uint4*>(p);
  return t.b;
}

typedef __attribute__((address_space(3))) void lds_void;
typedef __attribute__((address_space(1))) void g_void;
__device__ __forceinline__ void gl_lds16(const void* g, void* l) {
  __builtin_amdgcn_global_load_lds((g_void*)g, (lds_void*)l, 16, 0, 0);
}

__device__ __forceinline__ f32x4 mfma16(bf16x8 a, bf16x8 b, f32x4 c) {
  return __builtin_amdgcn_mfma_f32_16x16x32_bf16(a, b, c, 0, 0, 0);
}

#define SBAR() __builtin_amdgcn_s_barrier()

// ---------------- K0a: x f32 -> bf16 (8 elems/thread) -----------------------
__global__ void cvt_bf16(const float* __restrict__ src, u16* __restrict__ dst, int n8) {
  int i = blockIdx.x * blockDim.x + threadIdx.x;
  if (i >= n8) return;
  const float4* s = reinterpret_cast<const float4*>(src) + (size_t)i * 2;
  float4 a = s[0], b = s[1];
  union { u16 u[8]; uint4 v; } t;
  t.u[0] = f2bf(a.x); t.u[1] = f2bf(a.y); t.u[2] = f2bf(a.z); t.u[3] = f2bf(a.w);
  t.u[4] = f2bf(b.x); t.u[5] = f2bf(b.y); t.u[6] = f2bf(b.z); t.u[7] = f2bf(b.w);
  reinterpret_cast<uint4*>(dst)[i] = t.v;
}

// ---------------- K0b: all four weight matrices in one launch ---------------
__global__ void cvt_w(const float* __restrict__ Wq, const float* __restrict__ Wk,
                      const float* __restrict__ Wv, const float* __restrict__ Wo,
                      u16* __restrict__ wqkv, u16* __restrict__ wobf) {
  int idx = blockIdx.x * blockDim.x + threadIdx.x;   // 0 .. 131071
  int w = idx >> 15;                                  // 32768 uint4 per matrix
  int off = idx & 32767;
  const float* s = (w == 0) ? Wq : (w == 1) ? Wk : (w == 2) ? Wv : Wo;
  const float4* sp = reinterpret_cast<const float4*>(s) + (size_t)off * 2;
  float4 a = sp[0], b = sp[1];
  union { u16 u[8]; uint4 v; } t;
  t.u[0] = f2bf(a.x); t.u[1] = f2bf(a.y); t.u[2] = f2bf(a.z); t.u[3] = f2bf(a.w);
  t.u[4] = f2bf(b.x); t.u[5] = f2bf(b.y); t.u[6] = f2bf(b.z); t.u[7] = f2bf(b.w);
  if (w < 3) reinterpret_cast<uint4*>(wqkv)[w * 32768 + off] = t.v;
  else       reinterpret_cast<uint4*>(wobf)[off] = t.v;
}

// ---------------- K1: qkv = x_bf @ Wqkv^T + bias ----------------------------
// 256x256 tile, 8 waves (2Mx4N), K-halved 8-phase pipeline with counted vmcnt.
// Chunk-involution swizzle for conflict-free ds_read_b128 (round-4 verified).
#define K1_MFMA(MB)                                                         \
  __builtin_amdgcn_s_setprio(1);                                            \
  _Pragma("unroll") for (int i = 0; i < 4; i++)                             \
  _Pragma("unroll") for (int j = 0; j < 4; j++)                             \
    acc[(MB) + i][j] = mfma16(af[i], bfv[j], acc[(MB) + i][j]);             \
  __builtin_amdgcn_s_setprio(0);

#define K1_READA(E, HH, MB)                                                 \
  _Pragma("unroll") for (int i = 0; i < 4; i++)                             \
    af[i] = ld8(ldsA + ((E) * 2 + (HH)) * 8192 +                            \
                (wr * 128 + ((MB) + i) * 16 + l15) * 32 + xr8);

#define K1_READB(E, HH)                                                     \
  _Pragma("unroll") for (int j = 0; j < 4; j++)                             \
    bfv[j] = ld8(ldsB + ((E) * 2 + (HH)) * 8192 +                           \
                 (wc * 64 + j * 16 + l15) * 32 + xr8);

__global__ __launch_bounds__(512, 2) void k1_qkv(
    const u16* __restrict__ xbf,    // [M][512]
    const u16* __restrict__ wqkv,   // [1536][512]
    const float* __restrict__ bq, const float* __restrict__ bk, const float* __restrict__ bv,
    u16* __restrict__ qkv)          // [M][1536]
{
  __shared__ u16 lds[65536];        // 128 KiB: A = [0,32768), B = [32768,65536)
  u16* ldsA = lds;
  u16* ldsB = lds + 32768;

  const int tid = threadIdx.x;
  const int lane = tid & 63, wid = tid >> 6;
  const int wr = wid >> 2, wc = wid & 3;       // 2 x 4 wave grid
  const int g4 = lane >> 4, l15 = lane & 15;
  const int xr8 = (g4 ^ ((l15 >> 1) & 3)) * 8;   // swizzled chunk offset (elems)

  // XCD-chunked bijective swizzle (gridDim.x % 8 == 0 by construction)
  const int cpx = gridDim.x >> 3;
  const int logical = (blockIdx.x & 7) * cpx + (blockIdx.x >> 3);
  const int m0 = (logical / 6) * 256;
  const int n0 = (logical % 6) * 256;

  const u16* ga = xbf + (size_t)m0 * E_;
  const u16* gb = wqkv + (size_t)n0 * E_;

  const int r0 = tid >> 2;                             // 0..127
  const int c0 = ((tid & 3) ^ ((tid >> 3) & 3)) * 8;   // pre-swizzled source chunk

  auto stageA = [&](int e, int h, int kt) {
    const int kc = kt * 64 + h * 32;
    u16* base = ldsA + (e * 2 + h) * 8192;
    gl_lds16(ga + (size_t)r0 * E_ + kc + c0, base + wid * 512);
    gl_lds16(ga + (size_t)(r0 + 128) * E_ + kc + c0, base + 4096 + wid * 512);
  };
  auto stageB = [&](int e, int h, int kt) {
    const int kc = kt * 64 + h * 32;
    u16* base = ldsB + (e * 2 + h) * 8192;
    gl_lds16(gb + (size_t)r0 * E_ + kc + c0, base + wid * 512);
    gl_lds16(gb + (size_t)(r0 + 128) * E_ + kc + c0, base + 4096 + wid * 512);
  };

  f32x4 acc[8][4];
#pragma unroll
  for (int i = 0; i < 8; i++)
#pragma unroll
    for (int j = 0; j < 4; j++) { f32x4 z = {0.f, 0.f, 0.f, 0.f}; acc[i][j] = z; }

  // prologue: 6 stages (12 loads); wait for tile0-h0 (oldest 2 stages)
  stageA(0, 0, 0); stageB(0, 0, 0);
  stageA(0, 1, 0); stageB(0, 1, 0);
  stageA(1, 0, 1); stageB(1, 0, 1);
  asm volatile("s_waitcnt vmcnt(8)" ::: "memory");
  SBAR();

#pragma unroll 2
  for (int s = 0; s < 8; ++s) {
    const int e = s & 1;
    bf16x8 af[4], bfv[4];
    // ---- P0: h=0, mi 0-3 ----
    K1_READA(e, 0, 0)
    K1_READB(e, 0)
    if (s < 7) stageA(e ^ 1, 1, s + 1);
    SBAR();
    K1_MFMA(0)
    SBAR();
    // ---- P1: h=0, mi 4-7 (B reused) ----
    K1_READA(e, 0, 4)
    if (s < 7) stageB(e ^ 1, 1, s + 1);
    if (s < 7) { asm volatile("s_waitcnt vmcnt(8)" ::: "memory"); }
    else       { asm volatile("s_waitcnt vmcnt(0)" ::: "memory"); }
    SBAR();
    K1_MFMA(4)
    SBAR();
    // ---- P2: h=1, mi 0-3 ----
    K1_READA(e, 1, 0)
    K1_READB(e, 1)
    if (s < 6) stageA(e, 0, s + 2);
    SBAR();
    K1_MFMA(0)
    SBAR();
    // ---- P3: h=1, mi 4-7 ----
    K1_READA(e, 1, 4)
    if (s < 6) stageB(e, 0, s + 2);
    if (s < 6)      { asm volatile("s_waitcnt vmcnt(8)" ::: "memory"); }
    else if (s == 6){ asm volatile("s_waitcnt vmcnt(4)" ::: "memory"); }
    SBAR();
    K1_MFMA(4)
    SBAR();
  }

  // epilogue: + bias, store bf16 token-major, ni innermost (full-line writes)
  float bias4[4];
#pragma unroll
  for (int ni = 0; ni < 4; ni++) {
    const int fcol = n0 + wc * 64 + ni * 16 + l15;
    bias4[ni] = fcol < 512 ? bq[fcol] : (fcol < 1024 ? bk[fcol - 512] : bv[fcol - 1024]);
  }
  const int fbase = n0 + wc * 64 + l15;
#pragma unroll
  for (int mi = 0; mi < 8; mi++)
#pragma unroll
    for (int r = 0; r < 4; r++) {
      const size_t row = m0 + wr * 128 + mi * 16 + g4 * 4 + r;
      u16* dst = qkv + row * NF + fbase;
#pragma unroll
      for (int ni = 0; ni < 4; ni++)
        dst[ni * 16] = f2bf(acc[mi][ni][r] + bias4[ni]);
    }
}

// ---------------- K2: per-(b,p,h) causal attention over T=64, D=64 ----------
__global__ __launch_bounds__(256) void k2_attn(
    const u16* __restrict__ qkv,   // [nb*MCH][1536], token n = b*MCH + t*P_ + p
    u16* __restrict__ o)           // [nb*MCH][512]
{
  __shared__ u16 Pl[4][64 * 72];
  const int tid = threadIdx.x, lane = tid & 63, wid = tid >> 6;
  const int gw = blockIdx.x * 4 + wid;
  const int b = gw >> 11;                  // 2048 waves per batch chunk
  const int g = gw & 2047;
  const int h = g & 7, p = g >> 3;
  const int g4 = lane >> 4;
  const size_t ts = (size_t)P_ * NF;       // t-stride in elements
  const u16* qb = qkv + (size_t)b * MCH * NF + (size_t)p * NF + h * D_;
  const u16* kb = qb + 512;
  const u16* vb = qb + 1024;
  u16* ob = o + (size_t)b * MCH * E_;

  bf16x8 qf[4][2], kf[4][2];
#pragma unroll
  for (int i = 0; i < 4; i++)
#pragma unroll
    for (int ks = 0; ks < 2; ks++) {
      const int rr = i * 16 + (lane & 15);
      const int dc = ks * 32 + g4 * 8;
      qf[i][ks] = ld8(qb + (size_t)rr * ts + dc);
      kf[i][ks] = ld8(kb + (size_t)rr * ts + dc);
    }
  f32x4 S[4][4];
#pragma unroll
  for (int i = 0; i < 4; i++)
#pragma unroll
    for (int j = 0; j < 4; j++) { f32x4 z = {0.f, 0.f, 0.f, 0.f}; S[i][j] = z; }
#pragma unroll
  for (int ks = 0; ks < 2; ks++)
#pragma unroll
    for (int mi = 0; mi < 4; mi++)
#pragma unroll
      for (int ni = 0; ni < 4; ni++)
        S[mi][ni] = mfma16(qf[mi][ks], kf[ni][ks], S[mi][ni]);

  u16* pw = &Pl[wid][0];
#pragma unroll
  for (int mi = 0; mi < 4; mi++)
#pragma unroll
    for (int r = 0; r < 4; r++) {
      const int t = mi * 16 + g4 * 4 + r;
      float v[4]; float mx = -1e30f;
#pragma unroll
      for (int ni = 0; ni < 4; ni++) {
        const int s = ni * 16 + (lane & 15);
        v[ni] = (s <= t) ? S[mi][ni][r] * 0.125f : -1e30f;
        mx = fmaxf(mx, v[ni]);
      }
      mx = fmaxf(mx, __shfl_xor(mx, 1));
      mx = fmaxf(mx, __shfl_xor(mx, 2));
      mx = fmaxf(mx, __shfl_xor(mx, 4));
      mx = fmaxf(mx, __shfl_xor(mx, 8));
      float sum = 0.f; float pv[4];
#pragma unroll
      for (int ni = 0; ni < 4; ni++) {
        const int s = ni * 16 + (lane & 15);
        pv[ni] = (s <= t) ? __expf(v[ni] - mx) : 0.f;
        sum += pv[ni];
      }
      sum += __shfl_xor(sum, 1);
      sum += __shfl_xor(sum, 2);
      sum += __shfl_xor(sum, 4);
      sum += __shfl_xor(sum, 8);
      const float inv = 1.0f / sum;
#pragma unroll
      for (int ni = 0; ni < 4; ni++) {
        const int s = ni * 16 + (lane & 15);
        pw[t * 72 + s] = f2bf(pv[ni] * inv);
      }
    }
  __syncthreads();

  f32x4 O[4][4];
#pragma unroll
  for (int i = 0; i < 4; i++)
#pragma unroll
    for (int j = 0; j < 4; j++) { f32x4 z = {0.f, 0.f, 0.f, 0.f}; O[i][j] = z; }
#pragma unroll
  for (int ks = 0; ks < 2; ks++) {
    bf16x8 pa[4], vf[4];
#pragma unroll
    for (int mi = 0; mi < 4; mi++)
      pa[mi] = ld8(pw + (mi * 16 + (lane & 15)) * 72 + ks * 32 + g4 * 8);
#pragma unroll
    for (int ni = 0; ni < 4; ni++) {
      union { u16 u[8]; bf16x8 b; } tv;
#pragma unroll
      for (int j = 0; j < 8; j++) {
        const int s = ks * 32 + g4 * 8 + j;
        tv.u[j] = vb[(size_t)s * ts + ni * 16 + (lane & 15)];
      }
      vf[ni] = tv.b;
    }
#pragma unroll
    for (int mi = 0; mi < 4; mi++)
#pragma unroll
      for (int ni = 0; ni < 4; ni++)
        O[mi][ni] = mfma16(pa[mi], vf[ni], O[mi][ni]);
  }
#pragma unroll
  for (int mi = 0; mi < 4; mi++)
#pragma unroll
    for (int ni = 0; ni < 4; ni++)
#pragma unroll
      for (int r = 0; r < 4; r++) {
        const int t = mi * 16 + g4 * 4 + r;
        const int d = ni * 16 + (lane & 15);
        ob[((size_t)t * P_ + p) * E_ + h * D_ + d] = f2bf(O[mi][ni][r]);
      }
}

// ---------------- K3: out = LN(x + o @ Wo^T + bo) ---------------------------
// BM=64 x full N=512, 8 waves (each 64 cols), acc[4][4] (64 regs).
// A-frags direct from global (L2-shared across waves); B (Wo) in 64KB
// swizzled LDS dbuf; counted-vmcnt 2-barrier loop. 66KB LDS + ~115 regs
// -> 2 blocks/CU (16 waves) occupancy.
__global__ __launch_bounds__(512, 4) void k3_out(
    const u16* __restrict__ obf,   // [M][512]
    const u16* __restrict__ wo,    // [512][512]
    const float* __restrict__ bo,
    const float* __restrict__ x,   // [M][512] f32
    const float* __restrict__ lng, const float* __restrict__ lnb,
    float* __restrict__ out)       // [M][512] f32
{
  __shared__ u16 Bs[2][512 * 32];   // 64 KiB, chunk-swizzled rows (64B pitch)
  __shared__ float redS[64][8];
  __shared__ float redQ[64][8];
  const int tid = threadIdx.x, lane = tid & 63, wid = tid >> 6;  // 8 waves
  const int g4 = lane >> 4, l15 = lane & 15;
  const int xr8 = (g4 ^ ((l15 >> 1) & 3)) * 8;
  const int m0 = blockIdx.x * 64;

  // B staging: thread covers 4 groups of 64 chunks; lane l -> chunk l in group.
  const int srow = lane >> 2;                                // 0..15 within group
  const int scol = ((lane & 3) ^ ((srow >> 1) & 3)) * 8;     // pre-swizzled src chunk

  const u16* ga = obf + (size_t)m0 * E_;

  auto stageB = [&](int e, int kt) {
    const int k0 = kt * 32;
#pragma unroll
    for (int p = 0; p < 4; ++p) {
      const int gz = wid * 4 + p;                            // 0..31: 16 rows each
      gl_lds16(wo + (size_t)(gz * 16 + srow) * E_ + k0 + scol, &Bs[e][gz * 512]);
    }
  };

  f32x4 acc[4][4];
#pragma unroll
  for (int i = 0; i < 4; i++)
#pragma unroll
    for (int j = 0; j < 4; j++) { f32x4 z = {0.f, 0.f, 0.f, 0.f}; acc[i][j] = z; }

  stageB(0, 0);
  asm volatile("s_waitcnt vmcnt(0)" ::: "memory");
  SBAR();

#pragma unroll 2
  for (int kt = 0; kt < 16; ++kt) {
    const int e = kt & 1;
    bf16x8 af[4], bfv[4];
    // A-frags direct from global (L2 after first wave touches the line)
#pragma unroll
    for (int mi = 0; mi < 4; mi++)
      af[mi] = ld8(ga + (size_t)(mi * 16 + l15) * E_ + kt * 32 + g4 * 8);
    if (kt < 15) {
      stageB(e ^ 1, kt + 1);
      // queue: [stage(e) 4][af 4][stage(e^1) 4] -> drain to 4: af + stage(e) done
      asm volatile("s_waitcnt vmcnt(4)" ::: "memory");
    } else {
      asm volatile("s_waitcnt vmcnt(0)" ::: "memory");
    }
    SBAR();
#pragma unroll
    for (int ni = 0; ni < 4; ni++)
      bfv[ni] = ld8(&Bs[e][(wid * 64 + ni * 16 + l15) * 32 + xr8]);
    __builtin_amdgcn_s_setprio(1);
#pragma unroll
    for (int mi = 0; mi < 4; mi++)
#pragma unroll
      for (int ni = 0; ni < 4; ni++)
        acc[mi][ni] = mfma16(af[mi], bfv[ni], acc[mi][ni]);
    __builtin_amdgcn_s_setprio(0);
    SBAR();   // protects Bs[e] from next iteration's restage
  }

  // epilogue: y = acc + bo + x ; LayerNorm over 512 cols
  const int fb = wid * 64 + l15;
  float gg[4], bb[4], bof[4];
#pragma unroll
  for (int ni = 0; ni < 4; ni++) {
    const int f = fb + ni * 16;
    gg[ni] = lng[f]; bb[ni] = lnb[f]; bof[ni] = bo[f];
  }
#pragma unroll
  for (int mi = 0; mi < 4; mi++)
#pragma unroll
    for (int r = 0; r < 4; r++) {
      const int n = m0 + mi * 16 + g4 * 4 + r;
#pragma unroll
      for (int ni = 0; ni < 4; ni++)
        acc[mi][ni][r] += bof[ni] + x[(size_t)n * E_ + fb + ni * 16];
    }
#pragma unroll
  for (int mi = 0; mi < 4; mi++)
#pragma unroll
    for (int r = 0; r < 4; r++) {
      float s = 0.f, q = 0.f;
#pragma unroll
      for (int ni = 0; ni < 4; ni++) { const float y = acc[mi][ni][r]; s += y; q += y * y; }
      s += __shfl_xor(s, 1); q += __shfl_xor(q, 1);
      s += __shfl_xor(s, 2); q += __shfl_xor(q, 2);
      s += __shfl_xor(s, 4); q += __shfl_xor(q, 4);
      s += __shfl_xor(s, 8); q += __shfl_xor(q, 8);
      if (l15 == 0) {
        const int rl = mi * 16 + g4 * 4 + r;
        redS[rl][wid] = s; redQ[rl][wid] = q;
      }
    }
  __syncthreads();
#pragma unroll
  for (int mi = 0; mi < 4; mi++)
#pragma unroll
    for (int r = 0; r < 4; r++) {
      const int rl = mi * 16 + g4 * 4 + r;
      float Sx = 0.f, Qx = 0.f;
#pragma unroll
      for (int w = 0; w < 8; w++) { Sx += redS[rl][w]; Qx += redQ[rl][w]; }
      const float mean = Sx * (1.0f / 512.0f);
      const float var = Qx * (1.0f / 512.0f) - mean * mean;
      const float rs = rsqrtf(var + 1e-5f);
      const int n = m0 + rl;
#pragma unroll
      for (int ni = 0; ni < 4; ni++)
        out[(size_t)n * E_ + fb + ni * 16] = (acc[mi][ni][r] - mean) * rs * gg[ni] + bb[ni];
    }
}

extern "C" void kernel_launch(void* const* d_in, const int* in_sizes, int n_in,
                              void* d_out, int out_size, void* d_ws, size_t ws_size,
                              hipStream_t stream) {
  const float* x   = (const float*)d_in[0];
  const float* Wq  = (const float*)d_in[1];
  const float* bq  = (const float*)d_in[2];
  const float* Wk  = (const float*)d_in[3];
  const float* bk  = (const float*)d_in[4];
  const float* Wv  = (const float*)d_in[5];
  const float* bv  = (const float*)d_in[6];
  const float* Wo  = (const float*)d_in[7];
  const float* bo  = (const float*)d_in[8];
  const float* lng = (const float*)d_in[9];
  const float* lnb = (const float*)d_in[10];
  float* out = (float*)d_out;
  uint8_t* ws = (uint8_t*)d_ws;

  const size_t NEED_BIG = 270532608ULL;
  if (ws_size >= NEED_BIG) {
    u16* wqkv = (u16*)(ws);
    u16* wobf = (u16*)(ws + 1572864);
    u16* xbf  = (u16*)(ws + 2097152);         // 64 MiB ; obf aliases after k1
    u16* qkvc = (u16*)(ws + 69206016);        // 192 MiB
    u16* obf  = xbf;

    cvt_w<<<512, 256, 0, stream>>>(Wq, Wk, Wv, Wo, wqkv, wobf);
    cvt_bf16<<<16384, 256, 0, stream>>>(x, xbf, B_ * MCH * E_ / 8);
    k1_qkv<<<1536, 512, 0, stream>>>(xbf, wqkv, bq, bk, bv, qkvc);   // 256 m x 6 n
    k2_attn<<<2048, 256, 0, stream>>>(qkvc, obf);
    k3_out<<<1024, 512, 0, stream>>>(obf, wobf, bo, x, lng, lnb, out);
  } else {
    u16* xbf  = (u16*)(ws);                   // 16 MiB
    u16* qkvc = (u16*)(ws + 16777216);        // 48 MiB
    u16* obf  = (u16*)(ws + 67108864);        // 16 MiB
    u16* wqkv = (u16*)(ws + 83886080);
    u16* wobf = (u16*)(ws + 85458944);

    cvt_w<<<512, 256, 0, stream>>>(Wq, Wk, Wv, Wo, wqkv, wobf);
    for (int b = 0; b < B_; ++b) {
      const float* xb = x + (size_t)b * MCH * E_;
      cvt_bf16<<<4096, 256, 0, stream>>>(xb, xbf, MCH * E_ / 8);
      k1_qkv<<<384, 512, 0, stream>>>(xbf, wqkv, bq, bk, bv, qkvc);  // 64 m x 6 n
      k2_attn<<<512, 256, 0, stream>>>(qkvc, obf);
      k3_out<<<256, 512, 0, stream>>>(obf, wobf, bo, xb, lng, lnb, out + (size_t)b * MCH * E_);
    }
  }
}

// Round 6
// 398.337 us; speedup vs baseline: 1.1121x; 1.1121x over previous
//
#include <hip/hip_runtime.h>
#include <stdint.h>

#define B_ 4
#define T_ 64
#define P_ 256
#define E_ 512
#define H_ 8
#define D_ 64
#define NF 1536
#define MCH 16384   // tokens per b-chunk (T_*P_)

typedef unsigned short u16;
typedef __attribute__((ext_vector_type(8))) __bf16 bf16x8;
typedef __attribute__((ext_vector_type(4))) float f32x4;

__device__ __forceinline__ u16 f2bf(float x) {
  union { float f; uint32_t u; } a; a.f = x;
  uint32_t u = a.u;
  uint32_t r = (u + 0x7FFFu + ((u >> 16) & 1u)) >> 16;
  return (u16)r;
}

__device__ __forceinline__ bf16x8 ld8(const u16* p) {
  union { uint4 u; bf16x8 b; } t;
  t.u = *reinterpret_cast<const uint4*>(p);
  return t.b;
}

typedef __attribute__((address_space(3))) void lds_void;
typedef __attribute__((address_space(1))) void g_void;
__device__ __forceinline__ void gl_lds16(const void* g, void* l) {
  __builtin_amdgcn_global_load_lds((g_void*)g, (lds_void*)l, 16, 0, 0);
}

__device__ __forceinline__ f32x4 mfma16(bf16x8 a, bf16x8 b, f32x4 c) {
  return __builtin_amdgcn_mfma_f32_16x16x32_bf16(a, b, c, 0, 0, 0);
}

#define SBAR() __builtin_amdgcn_s_barrier()

// ---------------- K0a: x f32 -> bf16 (8 elems/thread) -----------------------
__global__ void cvt_bf16(const float* __restrict__ src, u16* __restrict__ dst, int n8) {
  int i = blockIdx.x * blockDim.x + threadIdx.x;
  if (i >= n8) return;
  const float4* s = reinterpret_cast<const float4*>(src) + (size_t)i * 2;
  float4 a = s[0], b = s[1];
  union { u16 u[8]; uint4 v; } t;
  t.u[0] = f2bf(a.x); t.u[1] = f2bf(a.y); t.u[2] = f2bf(a.z); t.u[3] = f2bf(a.w);
  t.u[4] = f2bf(b.x); t.u[5] = f2bf(b.y); t.u[6] = f2bf(b.z); t.u[7] = f2bf(b.w);
  reinterpret_cast<uint4*>(dst)[i] = t.v;
}

// ---------------- K0b: all four weight matrices in one launch ---------------
__global__ void cvt_w(const float* __restrict__ Wq, const float* __restrict__ Wk,
                      const float* __restrict__ Wv, const float* __restrict__ Wo,
                      u16* __restrict__ wqkv, u16* __restrict__ wobf) {
  int idx = blockIdx.x * blockDim.x + threadIdx.x;   // 0 .. 131071
  int w = idx >> 15;                                  // 32768 uint4 per matrix
  int off = idx & 32767;
  const float* s = (w == 0) ? Wq : (w == 1) ? Wk : (w == 2) ? Wv : Wo;
  const float4* sp = reinterpret_cast<const float4*>(s) + (size_t)off * 2;
  float4 a = sp[0], b = sp[1];
  union { u16 u[8]; uint4 v; } t;
  t.u[0] = f2bf(a.x); t.u[1] = f2bf(a.y); t.u[2] = f2bf(a.z); t.u[3] = f2bf(a.w);
  t.u[4] = f2bf(b.x); t.u[5] = f2bf(b.y); t.u[6] = f2bf(b.z); t.u[7] = f2bf(b.w);
  if (w < 3) reinterpret_cast<uint4*>(wqkv)[w * 32768 + off] = t.v;
  else       reinterpret_cast<uint4*>(wobf)[off] = t.v;
}

// ---------------- K1: qkv = x_bf @ Wqkv^T + bias ----------------------------
// 256x256 tile, 8 waves (2Mx4N), K-halved 8-phase pipeline with counted vmcnt.
// Chunk-involution swizzle for conflict-free ds_read_b128 (round-4 verified).
#define K1_MFMA(MB)                                                         \
  __builtin_amdgcn_s_setprio(1);                                            \
  _Pragma("unroll") for (int i = 0; i < 4; i++)                             \
  _Pragma("unroll") for (int j = 0; j < 4; j++)                             \
    acc[(MB) + i][j] = mfma16(af[i], bfv[j], acc[(MB) + i][j]);             \
  __builtin_amdgcn_s_setprio(0);

#define K1_READA(E, HH, MB)                                                 \
  _Pragma("unroll") for (int i = 0; i < 4; i++)                             \
    af[i] = ld8(ldsA + ((E) * 2 + (HH)) * 8192 +                            \
                (wr * 128 + ((MB) + i) * 16 + l15) * 32 + xr8);

#define K1_READB(E, HH)                                                     \
  _Pragma("unroll") for (int j = 0; j < 4; j++)                             \
    bfv[j] = ld8(ldsB + ((E) * 2 + (HH)) * 8192 +                           \
                 (wc * 64 + j * 16 + l15) * 32 + xr8);

__global__ __launch_bounds__(512, 2) void k1_qkv(
    const u16* __restrict__ xbf,    // [M][512]
    const u16* __restrict__ wqkv,   // [1536][512]
    const float* __restrict__ bq, const float* __restrict__ bk, const float* __restrict__ bv,
    u16* __restrict__ qkv)          // [M][1536]
{
  __shared__ u16 lds[65536];        // 128 KiB: A = [0,32768), B = [32768,65536)
  u16* ldsA = lds;
  u16* ldsB = lds + 32768;

  const int tid = threadIdx.x;
  const int lane = tid & 63, wid = tid >> 6;
  const int wr = wid >> 2, wc = wid & 3;       // 2 x 4 wave grid
  const int g4 = lane >> 4, l15 = lane & 15;
  const int xr8 = (g4 ^ ((l15 >> 1) & 3)) * 8;   // swizzled chunk offset (elems)

  // XCD-chunked bijective swizzle (gridDim.x % 8 == 0 by construction)
  const int cpx = gridDim.x >> 3;
  const int logical = (blockIdx.x & 7) * cpx + (blockIdx.x >> 3);
  const int m0 = (logical / 6) * 256;
  const int n0 = (logical % 6) * 256;

  const u16* ga = xbf + (size_t)m0 * E_;
  const u16* gb = wqkv + (size_t)n0 * E_;

  const int r0 = tid >> 2;                             // 0..127
  const int c0 = ((tid & 3) ^ ((tid >> 3) & 3)) * 8;   // pre-swizzled source chunk

  auto stageA = [&](int e, int h, int kt) {
    const int kc = kt * 64 + h * 32;
    u16* base = ldsA + (e * 2 + h) * 8192;
    gl_lds16(ga + (size_t)r0 * E_ + kc + c0, base + wid * 512);
    gl_lds16(ga + (size_t)(r0 + 128) * E_ + kc + c0, base + 4096 + wid * 512);
  };
  auto stageB = [&](int e, int h, int kt) {
    const int kc = kt * 64 + h * 32;
    u16* base = ldsB + (e * 2 + h) * 8192;
    gl_lds16(gb + (size_t)r0 * E_ + kc + c0, base + wid * 512);
    gl_lds16(gb + (size_t)(r0 + 128) * E_ + kc + c0, base + 4096 + wid * 512);
  };

  f32x4 acc[8][4];
#pragma unroll
  for (int i = 0; i < 8; i++)
#pragma unroll
    for (int j = 0; j < 4; j++) { f32x4 z = {0.f, 0.f, 0.f, 0.f}; acc[i][j] = z; }

  // prologue: 6 stages (12 loads); wait for tile0-h0 (oldest 2 stages)
  stageA(0, 0, 0); stageB(0, 0, 0);
  stageA(0, 1, 0); stageB(0, 1, 0);
  stageA(1, 0, 1); stageB(1, 0, 1);
  asm volatile("s_waitcnt vmcnt(8)" ::: "memory");
  SBAR();

#pragma unroll 2
  for (int s = 0; s < 8; ++s) {
    const int e = s & 1;
    bf16x8 af[4], bfv[4];
    // ---- P0: h=0, mi 0-3 ----
    K1_READA(e, 0, 0)
    K1_READB(e, 0)
    if (s < 7) stageA(e ^ 1, 1, s + 1);
    SBAR();
    K1_MFMA(0)
    SBAR();
    // ---- P1: h=0, mi 4-7 (B reused) ----
    K1_READA(e, 0, 4)
    if (s < 7) stageB(e ^ 1, 1, s + 1);
    if (s < 7) { asm volatile("s_waitcnt vmcnt(8)" ::: "memory"); }
    else       { asm volatile("s_waitcnt vmcnt(0)" ::: "memory"); }
    SBAR();
    K1_MFMA(4)
    SBAR();
    // ---- P2: h=1, mi 0-3 ----
    K1_READA(e, 1, 0)
    K1_READB(e, 1)
    if (s < 6) stageA(e, 0, s + 2);
    SBAR();
    K1_MFMA(0)
    SBAR();
    // ---- P3: h=1, mi 4-7 ----
    K1_READA(e, 1, 4)
    if (s < 6) stageB(e, 0, s + 2);
    if (s < 6)      { asm volatile("s_waitcnt vmcnt(8)" ::: "memory"); }
    else if (s == 6){ asm volatile("s_waitcnt vmcnt(4)" ::: "memory"); }
    SBAR();
    K1_MFMA(4)
    SBAR();
  }

  // epilogue: + bias, store bf16 token-major, ni innermost (full-line writes)
  float bias4[4];
#pragma unroll
  for (int ni = 0; ni < 4; ni++) {
    const int fcol = n0 + wc * 64 + ni * 16 + l15;
    bias4[ni] = fcol < 512 ? bq[fcol] : (fcol < 1024 ? bk[fcol - 512] : bv[fcol - 1024]);
  }
  const int fbase = n0 + wc * 64 + l15;
#pragma unroll
  for (int mi = 0; mi < 8; mi++)
#pragma unroll
    for (int r = 0; r < 4; r++) {
      const size_t row = m0 + wr * 128 + mi * 16 + g4 * 4 + r;
      u16* dst = qkv + row * NF + fbase;
#pragma unroll
      for (int ni = 0; ni < 4; ni++)
        dst[ni * 16] = f2bf(acc[mi][ni][r] + bias4[ni]);
    }
}

// ---------------- K2: per-(b,p,h) causal attention over T=64, D=64 ----------
__global__ __launch_bounds__(256) void k2_attn(
    const u16* __restrict__ qkv,   // [nb*MCH][1536], token n = b*MCH + t*P_ + p
    u16* __restrict__ o)           // [nb*MCH][512]
{
  __shared__ u16 Pl[4][64 * 72];
  const int tid = threadIdx.x, lane = tid & 63, wid = tid >> 6;
  const int gw = blockIdx.x * 4 + wid;
  const int b = gw >> 11;                  // 2048 waves per batch chunk
  const int g = gw & 2047;
  const int h = g & 7, p = g >> 3;
  const int g4 = lane >> 4;
  const size_t ts = (size_t)P_ * NF;       // t-stride in elements
  const u16* qb = qkv + (size_t)b * MCH * NF + (size_t)p * NF + h * D_;
  const u16* kb = qb + 512;
  const u16* vb = qb + 1024;
  u16* ob = o + (size_t)b * MCH * E_;

  bf16x8 qf[4][2], kf[4][2];
#pragma unroll
  for (int i = 0; i < 4; i++)
#pragma unroll
    for (int ks = 0; ks < 2; ks++) {
      const int rr = i * 16 + (lane & 15);
      const int dc = ks * 32 + g4 * 8;
      qf[i][ks] = ld8(qb + (size_t)rr * ts + dc);
      kf[i][ks] = ld8(kb + (size_t)rr * ts + dc);
    }
  f32x4 S[4][4];
#pragma unroll
  for (int i = 0; i < 4; i++)
#pragma unroll
    for (int j = 0; j < 4; j++) { f32x4 z = {0.f, 0.f, 0.f, 0.f}; S[i][j] = z; }
#pragma unroll
  for (int ks = 0; ks < 2; ks++)
#pragma unroll
    for (int mi = 0; mi < 4; mi++)
#pragma unroll
      for (int ni = 0; ni < 4; ni++)
        S[mi][ni] = mfma16(qf[mi][ks], kf[ni][ks], S[mi][ni]);

  u16* pw = &Pl[wid][0];
#pragma unroll
  for (int mi = 0; mi < 4; mi++)
#pragma unroll
    for (int r = 0; r < 4; r++) {
      const int t = mi * 16 + g4 * 4 + r;
      float v[4]; float mx = -1e30f;
#pragma unroll
      for (int ni = 0; ni < 4; ni++) {
        const int s = ni * 16 + (lane & 15);
        v[ni] = (s <= t) ? S[mi][ni][r] * 0.125f : -1e30f;
        mx = fmaxf(mx, v[ni]);
      }
      mx = fmaxf(mx, __shfl_xor(mx, 1));
      mx = fmaxf(mx, __shfl_xor(mx, 2));
      mx = fmaxf(mx, __shfl_xor(mx, 4));
      mx = fmaxf(mx, __shfl_xor(mx, 8));
      float sum = 0.f; float pv[4];
#pragma unroll
      for (int ni = 0; ni < 4; ni++) {
        const int s = ni * 16 + (lane & 15);
        pv[ni] = (s <= t) ? __expf(v[ni] - mx) : 0.f;
        sum += pv[ni];
      }
      sum += __shfl_xor(sum, 1);
      sum += __shfl_xor(sum, 2);
      sum += __shfl_xor(sum, 4);
      sum += __shfl_xor(sum, 8);
      const float inv = 1.0f / sum;
#pragma unroll
      for (int ni = 0; ni < 4; ni++) {
        const int s = ni * 16 + (lane & 15);
        pw[t * 72 + s] = f2bf(pv[ni] * inv);
      }
    }
  __syncthreads();

  f32x4 O[4][4];
#pragma unroll
  for (int i = 0; i < 4; i++)
#pragma unroll
    for (int j = 0; j < 4; j++) { f32x4 z = {0.f, 0.f, 0.f, 0.f}; O[i][j] = z; }
#pragma unroll
  for (int ks = 0; ks < 2; ks++) {
    bf16x8 pa[4], vf[4];
#pragma unroll
    for (int mi = 0; mi < 4; mi++)
      pa[mi] = ld8(pw + (mi * 16 + (lane & 15)) * 72 + ks * 32 + g4 * 8);
#pragma unroll
    for (int ni = 0; ni < 4; ni++) {
      union { u16 u[8]; bf16x8 b; } tv;
#pragma unroll
      for (int j = 0; j < 8; j++) {
        const int s = ks * 32 + g4 * 8 + j;
        tv.u[j] = vb[(size_t)s * ts + ni * 16 + (lane & 15)];
      }
      vf[ni] = tv.b;
    }
#pragma unroll
    for (int mi = 0; mi < 4; mi++)
#pragma unroll
      for (int ni = 0; ni < 4; ni++)
        O[mi][ni] = mfma16(pa[mi], vf[ni], O[mi][ni]);
  }
#pragma unroll
  for (int mi = 0; mi < 4; mi++)
#pragma unroll
    for (int ni = 0; ni < 4; ni++)
#pragma unroll
      for (int r = 0; r < 4; r++) {
        const int t = mi * 16 + g4 * 4 + r;
        const int d = ni * 16 + (lane & 15);
        ob[((size_t)t * P_ + p) * E_ + h * D_ + d] = f2bf(O[mi][ni][r]);
      }
}

// ---------------- K3: out = LN(x + o @ Wo^T + bo) ---------------------------
// Barrier-free all-register thin GEMM. BM=64, 8 waves each owning 64 cols.
// A (obf) and B (Wo, L2-hot 512KB) loaded direct to registers, double-buffered
// one BK=64 step ahead with static even/odd rotation. No LDS staging, no
// K-loop barriers -> waves slip freely; latency hidden by 32-MFMA steps +
// wave overlap. LDS = 4KB (LN reduce only).
__global__ __launch_bounds__(512, 2) void k3_out(
    const u16* __restrict__ obf,   // [M][512]
    const u16* __restrict__ wo,    // [512][512]
    const float* __restrict__ bo,
    const float* __restrict__ x,   // [M][512] f32
    const float* __restrict__ lng, const float* __restrict__ lnb,
    float* __restrict__ out)       // [M][512] f32
{
  __shared__ float redS[64][8];
  __shared__ float redQ[64][8];
  const int tid = threadIdx.x, lane = tid & 63, wid = tid >> 6;  // 8 waves
  const int g4 = lane >> 4, l15 = lane & 15;
  const int m0 = blockIdx.x * 64;

  const u16* ga = obf + (size_t)m0 * E_;             // block's 64 A-rows
  const u16* gb = wo + (size_t)(wid * 64) * E_;      // wave's 64 Wo rows

  f32x4 acc[4][4];
#pragma unroll
  for (int i = 0; i < 4; i++)
#pragma unroll
    for (int j = 0; j < 4; j++) { f32x4 z = {0.f, 0.f, 0.f, 0.f}; acc[i][j] = z; }

  bf16x8 afA[4][2], afB[4][2], bfA[4][2], bfB[4][2];

#define K3_LOADA(AF, T)                                                     \
  _Pragma("unroll") for (int mi = 0; mi < 4; mi++)                          \
  _Pragma("unroll") for (int ks = 0; ks < 2; ks++)                          \
    AF[mi][ks] = ld8(ga + (size_t)(mi * 16 + l15) * E_ + (T) * 64 + ks * 32 + g4 * 8);
#define K3_LOADB(BF, T)                                                     \
  _Pragma("unroll") for (int ni = 0; ni < 4; ni++)                          \
  _Pragma("unroll") for (int ks = 0; ks < 2; ks++)                          \
    BF[ni][ks] = ld8(gb + (size_t)(ni * 16 + l15) * E_ + (T) * 64 + ks * 32 + g4 * 8);
#define K3_COMP(AF, BF)                                                     \
  _Pragma("unroll") for (int ks = 0; ks < 2; ks++)                          \
  _Pragma("unroll") for (int mi = 0; mi < 4; mi++)                          \
  _Pragma("unroll") for (int ni = 0; ni < 4; ni++)                          \
    acc[mi][ni] = mfma16(AF[mi][ks], BF[ni][ks], acc[mi][ni]);

  K3_LOADA(afA, 0)
  K3_LOADB(bfA, 0)
#pragma unroll
  for (int t = 0; t < 8; t += 2) {
    if (t + 1 < 8) { K3_LOADA(afB, t + 1) K3_LOADB(bfB, t + 1) }
    K3_COMP(afA, bfA)
    if (t + 2 < 8) { K3_LOADA(afA, t + 2) K3_LOADB(bfA, t + 2) }
    if (t + 1 < 8) { K3_COMP(afB, bfB) }
  }

  // epilogue: y = acc + bo + x ; LayerNorm over 512 cols
  const int fb = wid * 64 + l15;
  float gg[4], bb[4], bof[4];
#pragma unroll
  for (int ni = 0; ni < 4; ni++) {
    const int f = fb + ni * 16;
    gg[ni] = lng[f]; bb[ni] = lnb[f]; bof[ni] = bo[f];
  }
#pragma unroll
  for (int mi = 0; mi < 4; mi++)
#pragma unroll
    for (int r = 0; r < 4; r++) {
      const int n = m0 + mi * 16 + g4 * 4 + r;
#pragma unroll
      for (int ni = 0; ni < 4; ni++)
        acc[mi][ni][r] += bof[ni] + x[(size_t)n * E_ + fb + ni * 16];
    }
#pragma unroll
  for (int mi = 0; mi < 4; mi++)
#pragma unroll
    for (int r = 0; r < 4; r++) {
      float s = 0.f, q = 0.f;
#pragma unroll
      for (int ni = 0; ni < 4; ni++) { const float y = acc[mi][ni][r]; s += y; q += y * y; }
      s += __shfl_xor(s, 1); q += __shfl_xor(q, 1);
      s += __shfl_xor(s, 2); q += __shfl_xor(q, 2);
      s += __shfl_xor(s, 4); q += __shfl_xor(q, 4);
      s += __shfl_xor(s, 8); q += __shfl_xor(q, 8);
      if (l15 == 0) {
        const int rl = mi * 16 + g4 * 4 + r;
        redS[rl][wid] = s; redQ[rl][wid] = q;
      }
    }
  __syncthreads();
#pragma unroll
  for (int mi = 0; mi < 4; mi++)
#pragma unroll
    for (int r = 0; r < 4; r++) {
      const int rl = mi * 16 + g4 * 4 + r;
      float Sx = 0.f, Qx = 0.f;
#pragma unroll
      for (int w = 0; w < 8; w++) { Sx += redS[rl][w]; Qx += redQ[rl][w]; }
      const float mean = Sx * (1.0f / 512.0f);
      const float var = Qx * (1.0f / 512.0f) - mean * mean;
      const float rs = rsqrtf(var + 1e-5f);
      const int n = m0 + rl;
#pragma unroll
      for (int ni = 0; ni < 4; ni++)
        out[(size_t)n * E_ + fb + ni * 16] = (acc[mi][ni][r] - mean) * rs * gg[ni] + bb[ni];
    }
}

extern "C" void kernel_launch(void* const* d_in, const int* in_sizes, int n_in,
                              void* d_out, int out_size, void* d_ws, size_t ws_size,
                              hipStream_t stream) {
  const float* x   = (const float*)d_in[0];
  const float* Wq  = (const float*)d_in[1];
  const float* bq  = (const float*)d_in[2];
  const float* Wk  = (const float*)d_in[3];
  const float* bk  = (const float*)d_in[4];
  const float* Wv  = (const float*)d_in[5];
  const float* bv  = (const float*)d_in[6];
  const float* Wo  = (const float*)d_in[7];
  const float* bo  = (const float*)d_in[8];
  const float* lng = (const float*)d_in[9];
  const float* lnb = (const float*)d_in[10];
  float* out = (float*)d_out;
  uint8_t* ws = (uint8_t*)d_ws;

  const size_t NEED_BIG = 270532608ULL;
  if (ws_size >= NEED_BIG) {
    u16* wqkv = (u16*)(ws);
    u16* wobf = (u16*)(ws + 1572864);
    u16* xbf  = (u16*)(ws + 2097152);         // 64 MiB ; obf aliases after k1
    u16* qkvc = (u16*)(ws + 69206016);        // 192 MiB
    u16* obf  = xbf;

    cvt_w<<<512, 256, 0, stream>>>(Wq, Wk, Wv, Wo, wqkv, wobf);
    cvt_bf16<<<16384, 256, 0, stream>>>(x, xbf, B_ * MCH * E_ / 8);
    k1_qkv<<<1536, 512, 0, stream>>>(xbf, wqkv, bq, bk, bv, qkvc);   // 256 m x 6 n
    k2_attn<<<2048, 256, 0, stream>>>(qkvc, obf);
    k3_out<<<1024, 512, 0, stream>>>(obf, wobf, bo, x, lng, lnb, out);
  } else {
    u16* xbf  = (u16*)(ws);                   // 16 MiB
    u16* qkvc = (u16*)(ws + 16777216);        // 48 MiB
    u16* obf  = (u16*)(ws + 67108864);        // 16 MiB
    u16* wqkv = (u16*)(ws + 83886080);
    u16* wobf = (u16*)(ws + 85458944);

    cvt_w<<<512, 256, 0, stream>>>(Wq, Wk, Wv, Wo, wqkv, wobf);
    for (int b = 0; b < B_; ++b) {
      const float* xb = x + (size_t)b * MCH * E_;
      cvt_bf16<<<4096, 256, 0, stream>>>(xb, xbf, MCH * E_ / 8);
      k1_qkv<<<384, 512, 0, stream>>>(xbf, wqkv, bq, bk, bv, qkvc);  // 64 m x 6 n
      k2_attn<<<512, 256, 0, stream>>>(qkvc, obf);
      k3_out<<<256, 512, 0, stream>>>(obf, wobf, bo, xb, lng, lnb, out + (size_t)b * MCH * E_);
    }
  }
}

// Round 7
// 379.527 us; speedup vs baseline: 1.1673x; 1.0496x over previous
//
#include <hip/hip_runtime.h>
#include <stdint.h>

#define B_ 4
#define T_ 64
#define P_ 256
#define E_ 512
#define H_ 8
#define D_ 64
#define NF 1536
#define MCH 16384   // tokens per b-chunk (T_*P_)

typedef unsigned short u16;
typedef __attribute__((ext_vector_type(8))) __bf16 bf16x8;
typedef __attribute__((ext_vector_type(4))) float f32x4;

__device__ __forceinline__ u16 f2bf(float x) {
  union { float f; uint32_t u; } a; a.f = x;
  uint32_t u = a.u;
  uint32_t r = (u + 0x7FFFu + ((u >> 16) & 1u)) >> 16;
  return (u16)r;
}

__device__ __forceinline__ bf16x8 ld8(const u16* p) {
  union { uint4 u; bf16x8 b; } t;
  t.u = *reinterpret_cast<const uint4*>(p);
  return t.b;
}

typedef __attribute__((address_space(3))) void lds_void;
typedef __attribute__((address_space(1))) void g_void;
__device__ __forceinline__ void gl_lds16(const void* g, void* l) {
  __builtin_amdgcn_global_load_lds((g_void*)g, (lds_void*)l, 16, 0, 0);
}

__device__ __forceinline__ f32x4 mfma16(bf16x8 a, bf16x8 b, f32x4 c) {
  return __builtin_amdgcn_mfma_f32_16x16x32_bf16(a, b, c, 0, 0, 0);
}

#define SBAR() __builtin_amdgcn_s_barrier()

// ---------------- K0a: x f32 -> bf16 (8 elems/thread) -----------------------
__global__ void cvt_bf16(const float* __restrict__ src, u16* __restrict__ dst, int n8) {
  int i = blockIdx.x * blockDim.x + threadIdx.x;
  if (i >= n8) return;
  const float4* s = reinterpret_cast<const float4*>(src) + (size_t)i * 2;
  float4 a = s[0], b = s[1];
  union { u16 u[8]; uint4 v; } t;
  t.u[0] = f2bf(a.x); t.u[1] = f2bf(a.y); t.u[2] = f2bf(a.z); t.u[3] = f2bf(a.w);
  t.u[4] = f2bf(b.x); t.u[5] = f2bf(b.y); t.u[6] = f2bf(b.z); t.u[7] = f2bf(b.w);
  reinterpret_cast<uint4*>(dst)[i] = t.v;
}

// ---------------- K0b: all four weight matrices in one launch ---------------
__global__ void cvt_w(const float* __restrict__ Wq, const float* __restrict__ Wk,
                      const float* __restrict__ Wv, const float* __restrict__ Wo,
                      u16* __restrict__ wqkv, u16* __restrict__ wobf) {
  int idx = blockIdx.x * blockDim.x + threadIdx.x;   // 0 .. 131071
  int w = idx >> 15;                                  // 32768 uint4 per matrix
  int off = idx & 32767;
  const float* s = (w == 0) ? Wq : (w == 1) ? Wk : (w == 2) ? Wv : Wo;
  const float4* sp = reinterpret_cast<const float4*>(s) + (size_t)off * 2;
  float4 a = sp[0], b = sp[1];
  union { u16 u[8]; uint4 v; } t;
  t.u[0] = f2bf(a.x); t.u[1] = f2bf(a.y); t.u[2] = f2bf(a.z); t.u[3] = f2bf(a.w);
  t.u[4] = f2bf(b.x); t.u[5] = f2bf(b.y); t.u[6] = f2bf(b.z); t.u[7] = f2bf(b.w);
  if (w < 3) reinterpret_cast<uint4*>(wqkv)[w * 32768 + off] = t.v;
  else       reinterpret_cast<uint4*>(wobf)[off] = t.v;
}

// ---------------- K1: qkv = x_bf @ Wqkv^T + bias ----------------------------
// 256x256 tile, 8 waves (2Mx4N), K-halved 8-phase pipeline with counted vmcnt.
// Chunk-involution swizzle for conflict-free ds_read_b128 (round-4 verified).
#define K1_MFMA(MB)                                                         \
  __builtin_amdgcn_s_setprio(1);                                            \
  _Pragma("unroll") for (int i = 0; i < 4; i++)                             \
  _Pragma("unroll") for (int j = 0; j < 4; j++)                             \
    acc[(MB) + i][j] = mfma16(af[i], bfv[j], acc[(MB) + i][j]);             \
  __builtin_amdgcn_s_setprio(0);

#define K1_READA(E, HH, MB)                                                 \
  _Pragma("unroll") for (int i = 0; i < 4; i++)                             \
    af[i] = ld8(ldsA + ((E) * 2 + (HH)) * 8192 +                            \
                (wr * 128 + ((MB) + i) * 16 + l15) * 32 + xr8);

#define K1_READB(E, HH)                                                     \
  _Pragma("unroll") for (int j = 0; j < 4; j++)                             \
    bfv[j] = ld8(ldsB + ((E) * 2 + (HH)) * 8192 +                           \
                 (wc * 64 + j * 16 + l15) * 32 + xr8);

__global__ __launch_bounds__(512, 2) void k1_qkv(
    const u16* __restrict__ xbf,    // [M][512]
    const u16* __restrict__ wqkv,   // [1536][512]
    const float* __restrict__ bq, const float* __restrict__ bk, const float* __restrict__ bv,
    u16* __restrict__ qkv)          // [M][1536]
{
  __shared__ u16 lds[65536];        // 128 KiB: A = [0,32768), B = [32768,65536)
  u16* ldsA = lds;
  u16* ldsB = lds + 32768;

  const int tid = threadIdx.x;
  const int lane = tid & 63, wid = tid >> 6;
  const int wr = wid >> 2, wc = wid & 3;       // 2 x 4 wave grid
  const int g4 = lane >> 4, l15 = lane & 15;
  const int xr8 = (g4 ^ ((l15 >> 1) & 3)) * 8;   // swizzled chunk offset (elems)

  // XCD-chunked bijective swizzle (gridDim.x % 8 == 0 by construction)
  const int cpx = gridDim.x >> 3;
  const int logical = (blockIdx.x & 7) * cpx + (blockIdx.x >> 3);
  const int m0 = (logical / 6) * 256;
  const int n0 = (logical % 6) * 256;

  const u16* ga = xbf + (size_t)m0 * E_;
  const u16* gb = wqkv + (size_t)n0 * E_;

  const int r0 = tid >> 2;                             // 0..127
  const int c0 = ((tid & 3) ^ ((tid >> 3) & 3)) * 8;   // pre-swizzled source chunk

  auto stageA = [&](int e, int h, int kt) {
    const int kc = kt * 64 + h * 32;
    u16* base = ldsA + (e * 2 + h) * 8192;
    gl_lds16(ga + (size_t)r0 * E_ + kc + c0, base + wid * 512);
    gl_lds16(ga + (size_t)(r0 + 128) * E_ + kc + c0, base + 4096 + wid * 512);
  };
  auto stageB = [&](int e, int h, int kt) {
    const int kc = kt * 64 + h * 32;
    u16* base = ldsB + (e * 2 + h) * 8192;
    gl_lds16(gb + (size_t)r0 * E_ + kc + c0, base + wid * 512);
    gl_lds16(gb + (size_t)(r0 + 128) * E_ + kc + c0, base + 4096 + wid * 512);
  };

  f32x4 acc[8][4];
#pragma unroll
  for (int i = 0; i < 8; i++)
#pragma unroll
    for (int j = 0; j < 4; j++) { f32x4 z = {0.f, 0.f, 0.f, 0.f}; acc[i][j] = z; }

  // prologue: 6 stages (12 loads); wait for tile0-h0 (oldest 2 stages)
  stageA(0, 0, 0); stageB(0, 0, 0);
  stageA(0, 1, 0); stageB(0, 1, 0);
  stageA(1, 0, 1); stageB(1, 0, 1);
  asm volatile("s_waitcnt vmcnt(8)" ::: "memory");
  SBAR();

#pragma unroll 2
  for (int s = 0; s < 8; ++s) {
    const int e = s & 1;
    bf16x8 af[4], bfv[4];
    // ---- P0: h=0, mi 0-3 ----
    K1_READA(e, 0, 0)
    K1_READB(e, 0)
    if (s < 7) stageA(e ^ 1, 1, s + 1);
    SBAR();
    K1_MFMA(0)
    SBAR();
    // ---- P1: h=0, mi 4-7 (B reused) ----
    K1_READA(e, 0, 4)
    if (s < 7) stageB(e ^ 1, 1, s + 1);
    if (s < 7) { asm volatile("s_waitcnt vmcnt(8)" ::: "memory"); }
    else       { asm volatile("s_waitcnt vmcnt(0)" ::: "memory"); }
    SBAR();
    K1_MFMA(4)
    SBAR();
    // ---- P2: h=1, mi 0-3 ----
    K1_READA(e, 1, 0)
    K1_READB(e, 1)
    if (s < 6) stageA(e, 0, s + 2);
    SBAR();
    K1_MFMA(0)
    SBAR();
    // ---- P3: h=1, mi 4-7 ----
    K1_READA(e, 1, 4)
    if (s < 6) stageB(e, 0, s + 2);
    if (s < 6)      { asm volatile("s_waitcnt vmcnt(8)" ::: "memory"); }
    else if (s == 6){ asm volatile("s_waitcnt vmcnt(4)" ::: "memory"); }
    SBAR();
    K1_MFMA(4)
    SBAR();
  }

  // epilogue: + bias, store bf16 token-major, ni innermost (full-line writes)
  float bias4[4];
#pragma unroll
  for (int ni = 0; ni < 4; ni++) {
    const int fcol = n0 + wc * 64 + ni * 16 + l15;
    bias4[ni] = fcol < 512 ? bq[fcol] : (fcol < 1024 ? bk[fcol - 512] : bv[fcol - 1024]);
  }
  const int fbase = n0 + wc * 64 + l15;
#pragma unroll
  for (int mi = 0; mi < 8; mi++)
#pragma unroll
    for (int r = 0; r < 4; r++) {
      const size_t row = m0 + wr * 128 + mi * 16 + g4 * 4 + r;
      u16* dst = qkv + row * NF + fbase;
#pragma unroll
      for (int ni = 0; ni < 4; ni++)
        dst[ni * 16] = f2bf(acc[mi][ni][r] + bias4[ni]);
    }
}

// ---------------- K2: per-(b,p,h) causal attention over T=64, D=64 ----------
__global__ __launch_bounds__(256) void k2_attn(
    const u16* __restrict__ qkv,   // [nb*MCH][1536], token n = b*MCH + t*P_ + p
    u16* __restrict__ o)           // [nb*MCH][512]
{
  __shared__ u16 Pl[4][64 * 72];
  const int tid = threadIdx.x, lane = tid & 63, wid = tid >> 6;
  const int gw = blockIdx.x * 4 + wid;
  const int b = gw >> 11;                  // 2048 waves per batch chunk
  const int g = gw & 2047;
  const int h = g & 7, p = g >> 3;
  const int g4 = lane >> 4;
  const size_t ts = (size_t)P_ * NF;       // t-stride in elements
  const u16* qb = qkv + (size_t)b * MCH * NF + (size_t)p * NF + h * D_;
  const u16* kb = qb + 512;
  const u16* vb = qb + 1024;
  u16* ob = o + (size_t)b * MCH * E_;

  bf16x8 qf[4][2], kf[4][2];
#pragma unroll
  for (int i = 0; i < 4; i++)
#pragma unroll
    for (int ks = 0; ks < 2; ks++) {
      const int rr = i * 16 + (lane & 15);
      const int dc = ks * 32 + g4 * 8;
      qf[i][ks] = ld8(qb + (size_t)rr * ts + dc);
      kf[i][ks] = ld8(kb + (size_t)rr * ts + dc);
    }
  f32x4 S[4][4];
#pragma unroll
  for (int i = 0; i < 4; i++)
#pragma unroll
    for (int j = 0; j < 4; j++) { f32x4 z = {0.f, 0.f, 0.f, 0.f}; S[i][j] = z; }
#pragma unroll
  for (int ks = 0; ks < 2; ks++)
#pragma unroll
    for (int mi = 0; mi < 4; mi++)
#pragma unroll
      for (int ni = 0; ni < 4; ni++)
        S[mi][ni] = mfma16(qf[mi][ks], kf[ni][ks], S[mi][ni]);

  u16* pw = &Pl[wid][0];
#pragma unroll
  for (int mi = 0; mi < 4; mi++)
#pragma unroll
    for (int r = 0; r < 4; r++) {
      const int t = mi * 16 + g4 * 4 + r;
      float v[4]; float mx = -1e30f;
#pragma unroll
      for (int ni = 0; ni < 4; ni++) {
        const int s = ni * 16 + (lane & 15);
        v[ni] = (s <= t) ? S[mi][ni][r] * 0.125f : -1e30f;
        mx = fmaxf(mx, v[ni]);
      }
      mx = fmaxf(mx, __shfl_xor(mx, 1));
      mx = fmaxf(mx, __shfl_xor(mx, 2));
      mx = fmaxf(mx, __shfl_xor(mx, 4));
      mx = fmaxf(mx, __shfl_xor(mx, 8));
      float sum = 0.f; float pv[4];
#pragma unroll
      for (int ni = 0; ni < 4; ni++) {
        const int s = ni * 16 + (lane & 15);
        pv[ni] = (s <= t) ? __expf(v[ni] - mx) : 0.f;
        sum += pv[ni];
      }
      sum += __shfl_xor(sum, 1);
      sum += __shfl_xor(sum, 2);
      sum += __shfl_xor(sum, 4);
      sum += __shfl_xor(sum, 8);
      const float inv = 1.0f / sum;
#pragma unroll
      for (int ni = 0; ni < 4; ni++) {
        const int s = ni * 16 + (lane & 15);
        pw[t * 72 + s] = f2bf(pv[ni] * inv);
      }
    }
  __syncthreads();

  f32x4 O[4][4];
#pragma unroll
  for (int i = 0; i < 4; i++)
#pragma unroll
    for (int j = 0; j < 4; j++) { f32x4 z = {0.f, 0.f, 0.f, 0.f}; O[i][j] = z; }
#pragma unroll
  for (int ks = 0; ks < 2; ks++) {
    bf16x8 pa[4], vf[4];
#pragma unroll
    for (int mi = 0; mi < 4; mi++)
      pa[mi] = ld8(pw + (mi * 16 + (lane & 15)) * 72 + ks * 32 + g4 * 8);
#pragma unroll
    for (int ni = 0; ni < 4; ni++) {
      union { u16 u[8]; bf16x8 b; } tv;
#pragma unroll
      for (int j = 0; j < 8; j++) {
        const int s = ks * 32 + g4 * 8 + j;
        tv.u[j] = vb[(size_t)s * ts + ni * 16 + (lane & 15)];
      }
      vf[ni] = tv.b;
    }
#pragma unroll
    for (int mi = 0; mi < 4; mi++)
#pragma unroll
      for (int ni = 0; ni < 4; ni++)
        O[mi][ni] = mfma16(pa[mi], vf[ni], O[mi][ni]);
  }
#pragma unroll
  for (int mi = 0; mi < 4; mi++)
#pragma unroll
    for (int ni = 0; ni < 4; ni++)
#pragma unroll
      for (int r = 0; r < 4; r++) {
        const int t = mi * 16 + g4 * 4 + r;
        const int d = ni * 16 + (lane & 15);
        ob[((size_t)t * P_ + p) * E_ + h * D_ + d] = f2bf(O[mi][ni][r]);
      }
}

// ---------------- K3: out = LN(x + o @ Wo^T + bo) ---------------------------
// k1-style deep pipeline at BM=128 x BN=512 (full row -> fused LN).
// 8 waves each own 64 cols, acc[8][4]. LDS 160KB: A[e][h] 128x32 (8KB x4) +
// B[e][h] 512x32 (32KB x4); LN-reduce scratch aliased into A (dead by then).
// Uniform staging: 5 gl_lds16/thread per stage-call (A:1 + B:4) -> counted
// vmcnt(10) steady state (2 stage-calls in flight), tail 10/5/0.
__global__ __launch_bounds__(512, 2) void k3_out(
    const u16* __restrict__ obf,   // [M][512]
    const u16* __restrict__ wo,    // [512][512]
    const float* __restrict__ bo,
    const float* __restrict__ x,   // [M][512] f32
    const float* __restrict__ lng, const float* __restrict__ lnb,
    float* __restrict__ out)       // [M][512] f32
{
  __shared__ u16 S[81920];          // 160 KiB exactly
  u16* SA = S;                      // A[e][h] at (e*2+h)*4096 u16
  u16* SB = S + 16384;              // B[e][h] at (e*2+h)*16384 u16
  float* redS = (float*)S;          // aliases A[0] region after main loop
  float* redQ = (float*)S + 1024;

  const int tid = threadIdx.x, lane = tid & 63, wid = tid >> 6;  // 8 waves
  const int g4 = lane >> 4, l15 = lane & 15;
  const int xr8 = (g4 ^ ((l15 >> 1) & 3)) * 8;
  const int m0 = blockIdx.x * 128;

  const u16* ga = obf + (size_t)m0 * E_;
  const int r0 = tid >> 2;                             // 0..127
  const int c0 = ((tid & 3) ^ ((tid >> 3) & 3)) * 8;   // pre-swizzled src chunk

  // stage one (e,h) region: A 128x32 (1 load/thread) + B 512x32 (4 loads/thread)
  auto stage = [&](int e, int h, int kt) {
    const int kc = kt * 64 + h * 32;
    gl_lds16(ga + (size_t)r0 * E_ + kc + c0, SA + (e * 2 + h) * 4096 + wid * 512);
    u16* bb = SB + (e * 2 + h) * 16384;
#pragma unroll
    for (int p = 0; p < 4; ++p) {
      const int row = p * 128 + r0;
      gl_lds16(wo + (size_t)row * E_ + kc + c0, bb + p * 4096 + wid * 512);
    }
  };

#define K3_READA(E, HH)                                                     \
  _Pragma("unroll") for (int i = 0; i < 8; i++)                             \
    af[i] = ld8(SA + ((E) * 2 + (HH)) * 4096 + (i * 16 + l15) * 32 + xr8);
#define K3_READB(E, HH)                                                     \
  _Pragma("unroll") for (int j = 0; j < 4; j++)                             \
    bfv[j] = ld8(SB + ((E) * 2 + (HH)) * 16384 + (wid * 64 + j * 16 + l15) * 32 + xr8);
#define K3_MFMA()                                                           \
  __builtin_amdgcn_s_setprio(1);                                            \
  _Pragma("unroll") for (int i = 0; i < 8; i++)                             \
  _Pragma("unroll") for (int j = 0; j < 4; j++)                             \
    acc[i][j] = mfma16(af[i], bfv[j], acc[i][j]);                           \
  __builtin_amdgcn_s_setprio(0);

  f32x4 acc[8][4];
#pragma unroll
  for (int i = 0; i < 8; i++)
#pragma unroll
    for (int j = 0; j < 4; j++) { f32x4 z = {0.f, 0.f, 0.f, 0.f}; acc[i][j] = z; }

  // prologue: 3 stage-calls (15 loads); vmcnt(10) -> h0(0) ready
  stage(0, 0, 0);
  stage(0, 1, 0);
  stage(1, 0, 1);
  asm volatile("s_waitcnt vmcnt(10)" ::: "memory");
  SBAR();

#pragma unroll
  for (int t = 0; t < 8; ++t) {
    const int e = t & 1;
    bf16x8 af[8], bfv[4];
    // ---- P0: h=0 ----
    K3_READA(e, 0)
    K3_READB(e, 0)
    if (t < 7) stage(e ^ 1, 1, t + 1);         // h1 of next tile
    if (t < 7) { asm volatile("s_waitcnt vmcnt(10)" ::: "memory"); }
    else       { asm volatile("s_waitcnt vmcnt(0)" ::: "memory"); }
    SBAR();
    K3_MFMA()
    SBAR();
    // ---- P1: h=1 ----
    K3_READA(e, 1)
    K3_READB(e, 1)
    if (t < 6) stage(e, 0, t + 2);             // h0 of tile t+2
    if (t < 6)      { asm volatile("s_waitcnt vmcnt(10)" ::: "memory"); }
    else if (t == 6){ asm volatile("s_waitcnt vmcnt(5)" ::: "memory"); }
    SBAR();
    K3_MFMA()
    SBAR();
  }

  // epilogue: y = acc + bo + x ; LayerNorm over 512 cols
  const int fb = wid * 64 + l15;
  float gg[4], bb2[4], bof[4];
#pragma unroll
  for (int ni = 0; ni < 4; ni++) {
    const int f = fb + ni * 16;
    gg[ni] = lng[f]; bb2[ni] = lnb[f]; bof[ni] = bo[f];
  }
#pragma unroll
  for (int mi = 0; mi < 8; mi++)
#pragma unroll
    for (int r = 0; r < 4; r++) {
      const int n = m0 + mi * 16 + g4 * 4 + r;
#pragma unroll
      for (int ni = 0; ni < 4; ni++)
        acc[mi][ni][r] += bof[ni] + x[(size_t)n * E_ + fb + ni * 16];
    }
#pragma unroll
  for (int mi = 0; mi < 8; mi++)
#pragma unroll
    for (int r = 0; r < 4; r++) {
      float s = 0.f, q = 0.f;
#pragma unroll
      for (int ni = 0; ni < 4; ni++) { const float y = acc[mi][ni][r]; s += y; q += y * y; }
      s += __shfl_xor(s, 1); q += __shfl_xor(q, 1);
      s += __shfl_xor(s, 2); q += __shfl_xor(q, 2);
      s += __shfl_xor(s, 4); q += __shfl_xor(q, 4);
      s += __shfl_xor(s, 8); q += __shfl_xor(q, 8);
      if (l15 == 0) {
        const int rl = mi * 16 + g4 * 4 + r;
        redS[rl * 8 + wid] = s; redQ[rl * 8 + wid] = q;
      }
    }
  __syncthreads();
#pragma unroll
  for (int mi = 0; mi < 8; mi++)
#pragma unroll
    for (int r = 0; r < 4; r++) {
      const int rl = mi * 16 + g4 * 4 + r;
      float Sx = 0.f, Qx = 0.f;
#pragma unroll
      for (int w = 0; w < 8; w++) { Sx += redS[rl * 8 + w]; Qx += redQ[rl * 8 + w]; }
      const float mean = Sx * (1.0f / 512.0f);
      const float var = Qx * (1.0f / 512.0f) - mean * mean;
      const float rs = rsqrtf(var + 1e-5f);
      const int n = m0 + rl;
#pragma unroll
      for (int ni = 0; ni < 4; ni++)
        out[(size_t)n * E_ + fb + ni * 16] = (acc[mi][ni][r] - mean) * rs * gg[ni] + bb2[ni];
    }
}

extern "C" void kernel_launch(void* const* d_in, const int* in_sizes, int n_in,
                              void* d_out, int out_size, void* d_ws, size_t ws_size,
                              hipStream_t stream) {
  const float* x   = (const float*)d_in[0];
  const float* Wq  = (const float*)d_in[1];
  const float* bq  = (const float*)d_in[2];
  const float* Wk  = (const float*)d_in[3];
  const float* bk  = (const float*)d_in[4];
  const float* Wv  = (const float*)d_in[5];
  const float* bv  = (const float*)d_in[6];
  const float* Wo  = (const float*)d_in[7];
  const float* bo  = (const float*)d_in[8];
  const float* lng = (const float*)d_in[9];
  const float* lnb = (const float*)d_in[10];
  float* out = (float*)d_out;
  uint8_t* ws = (uint8_t*)d_ws;

  const size_t NEED_BIG = 270532608ULL;
  if (ws_size >= NEED_BIG) {
    u16* wqkv = (u16*)(ws);
    u16* wobf = (u16*)(ws + 1572864);
    u16* xbf  = (u16*)(ws + 2097152);         // 64 MiB ; obf aliases after k1
    u16* qkvc = (u16*)(ws + 69206016);        // 192 MiB
    u16* obf  = xbf;

    cvt_w<<<512, 256, 0, stream>>>(Wq, Wk, Wv, Wo, wqkv, wobf);
    cvt_bf16<<<16384, 256, 0, stream>>>(x, xbf, B_ * MCH * E_ / 8);
    k1_qkv<<<1536, 512, 0, stream>>>(xbf, wqkv, bq, bk, bv, qkvc);   // 256 m x 6 n
    k2_attn<<<2048, 256, 0, stream>>>(qkvc, obf);
    k3_out<<<512, 512, 0, stream>>>(obf, wobf, bo, x, lng, lnb, out);
  } else {
    u16* xbf  = (u16*)(ws);                   // 16 MiB
    u16* qkvc = (u16*)(ws + 16777216);        // 48 MiB
    u16* obf  = (u16*)(ws + 67108864);        // 16 MiB
    u16* wqkv = (u16*)(ws + 83886080);
    u16* wobf = (u16*)(ws + 85458944);

    cvt_w<<<512, 256, 0, stream>>>(Wq, Wk, Wv, Wo, wqkv, wobf);
    for (int b = 0; b < B_; ++b) {
      const float* xb = x + (size_t)b * MCH * E_;
      cvt_bf16<<<4096, 256, 0, stream>>>(xb, xbf, MCH * E_ / 8);
      k1_qkv<<<384, 512, 0, stream>>>(xbf, wqkv, bq, bk, bv, qkvc);  // 64 m x 6 n
      k2_attn<<<512, 256, 0, stream>>>(qkvc, obf);
      k3_out<<<128, 512, 0, stream>>>(obf, wobf, bo, xb, lng, lnb, out + (size_t)b * MCH * E_);
    }
  }
}

// Round 8
// 361.098 us; speedup vs baseline: 1.2268x; 1.0510x over previous
//
#include <hip/hip_runtime.h>
#include <stdint.h>

#define B_ 4
#define T_ 64
#define P_ 256
#define E_ 512
#define H_ 8
#define D_ 64
#define NF 1536
#define MCH 16384   // tokens per b-chunk (T_*P_)

typedef unsigned short u16;
typedef __attribute__((ext_vector_type(8))) __bf16 bf16x8;
typedef __attribute__((ext_vector_type(4))) float f32x4;

__device__ __forceinline__ u16 f2bf(float x) {
  union { float f; uint32_t u; } a; a.f = x;
  uint32_t u = a.u;
  uint32_t r = (u + 0x7FFFu + ((u >> 16) & 1u)) >> 16;
  return (u16)r;
}

__device__ __forceinline__ bf16x8 ld8(const u16* p) {
  union { uint4 u; bf16x8 b; } t;
  t.u = *reinterpret_cast<const uint4*>(p);
  return t.b;
}

typedef __attribute__((address_space(3))) void lds_void;
typedef __attribute__((address_space(1))) void g_void;
__device__ __forceinline__ void gl_lds16(const void* g, void* l) {
  __builtin_amdgcn_global_load_lds((g_void*)g, (lds_void*)l, 16, 0, 0);
}

__device__ __forceinline__ f32x4 mfma16(bf16x8 a, bf16x8 b, f32x4 c) {
  return __builtin_amdgcn_mfma_f32_16x16x32_bf16(a, b, c, 0, 0, 0);
}

#define SBAR() __builtin_amdgcn_s_barrier()

// ---------------- K0a: x f32 -> bf16 (8 elems/thread) -----------------------
__global__ void cvt_bf16(const float* __restrict__ src, u16* __restrict__ dst, int n8) {
  int i = blockIdx.x * blockDim.x + threadIdx.x;
  if (i >= n8) return;
  const float4* s = reinterpret_cast<const float4*>(src) + (size_t)i * 2;
  float4 a = s[0], b = s[1];
  union { u16 u[8]; uint4 v; } t;
  t.u[0] = f2bf(a.x); t.u[1] = f2bf(a.y); t.u[2] = f2bf(a.z); t.u[3] = f2bf(a.w);
  t.u[4] = f2bf(b.x); t.u[5] = f2bf(b.y); t.u[6] = f2bf(b.z); t.u[7] = f2bf(b.w);
  reinterpret_cast<uint4*>(dst)[i] = t.v;
}

// ---------------- K0b: all four weight matrices in one launch ---------------
__global__ void cvt_w(const float* __restrict__ Wq, const float* __restrict__ Wk,
                      const float* __restrict__ Wv, const float* __restrict__ Wo,
                      u16* __restrict__ wqkv, u16* __restrict__ wobf) {
  int idx = blockIdx.x * blockDim.x + threadIdx.x;   // 0 .. 131071
  int w = idx >> 15;                                  // 32768 uint4 per matrix
  int off = idx & 32767;
  const float* s = (w == 0) ? Wq : (w == 1) ? Wk : (w == 2) ? Wv : Wo;
  const float4* sp = reinterpret_cast<const float4*>(s) + (size_t)off * 2;
  float4 a = sp[0], b = sp[1];
  union { u16 u[8]; uint4 v; } t;
  t.u[0] = f2bf(a.x); t.u[1] = f2bf(a.y); t.u[2] = f2bf(a.z); t.u[3] = f2bf(a.w);
  t.u[4] = f2bf(b.x); t.u[5] = f2bf(b.y); t.u[6] = f2bf(b.z); t.u[7] = f2bf(b.w);
  if (w < 3) reinterpret_cast<uint4*>(wqkv)[w * 32768 + off] = t.v;
  else       reinterpret_cast<uint4*>(wobf)[off] = t.v;
}

// ---------------- shared GEMM pipeline macros (k1-proven) -------------------
#define GP_MFMA(MB)                                                         \
  __builtin_amdgcn_s_setprio(1);                                            \
  _Pragma("unroll") for (int i = 0; i < 4; i++)                             \
  _Pragma("unroll") for (int j = 0; j < 4; j++)                             \
    acc[(MB) + i][j] = mfma16(af[i], bfv[j], acc[(MB) + i][j]);             \
  __builtin_amdgcn_s_setprio(0);

#define GP_READA(E, HH, MB)                                                 \
  _Pragma("unroll") for (int i = 0; i < 4; i++)                             \
    af[i] = ld8(ldsA + ((E) * 2 + (HH)) * 8192 +                            \
                (wr * 128 + ((MB) + i) * 16 + l15) * 32 + xr8);

#define GP_READB(E, HH)                                                     \
  _Pragma("unroll") for (int j = 0; j < 4; j++)                             \
    bfv[j] = ld8(ldsB + ((E) * 2 + (HH)) * 8192 +                           \
                 (wc * 64 + j * 16 + l15) * 32 + xr8);

// K-loop body (identical schedule in k1 and k3_gemm); declares af/bfv.
#define GP_KLOOP()                                                          \
  stageA(0, 0, 0); stageB(0, 0, 0);                                         \
  stageA(0, 1, 0); stageB(0, 1, 0);                                         \
  stageA(1, 0, 1); stageB(1, 0, 1);                                         \
  asm volatile("s_waitcnt vmcnt(8)" ::: "memory");                          \
  SBAR();                                                                   \
  _Pragma("unroll 2") for (int s = 0; s < 8; ++s) {                         \
    const int e = s & 1;                                                    \
    bf16x8 af[4], bfv[4];                                                   \
    GP_READA(e, 0, 0)                                                       \
    GP_READB(e, 0)                                                          \
    if (s < 7) stageA(e ^ 1, 1, s + 1);                                     \
    SBAR();                                                                 \
    GP_MFMA(0)                                                              \
    SBAR();                                                                 \
    GP_READA(e, 0, 4)                                                       \
    if (s < 7) stageB(e ^ 1, 1, s + 1);                                     \
    if (s < 7) { asm volatile("s_waitcnt vmcnt(8)" ::: "memory"); }         \
    else       { asm volatile("s_waitcnt vmcnt(0)" ::: "memory"); }         \
    SBAR();                                                                 \
    GP_MFMA(4)                                                              \
    SBAR();                                                                 \
    GP_READA(e, 1, 0)                                                       \
    GP_READB(e, 1)                                                          \
    if (s < 6) stageA(e, 0, s + 2);                                         \
    SBAR();                                                                 \
    GP_MFMA(0)                                                              \
    SBAR();                                                                 \
    GP_READA(e, 1, 4)                                                       \
    if (s < 6) stageB(e, 0, s + 2);                                         \
    if (s < 6)      { asm volatile("s_waitcnt vmcnt(8)" ::: "memory"); }    \
    else if (s == 6){ asm volatile("s_waitcnt vmcnt(4)" ::: "memory"); }    \
    SBAR();                                                                 \
    GP_MFMA(4)                                                              \
    SBAR();                                                                 \
  }

// ---------------- K1: qkv = x_bf @ Wqkv^T + bias ----------------------------
__global__ __launch_bounds__(512, 2) void k1_qkv(
    const u16* __restrict__ xbf,    // [M][512]
    const u16* __restrict__ wqkv,   // [1536][512]
    const float* __restrict__ bq, const float* __restrict__ bk, const float* __restrict__ bv,
    u16* __restrict__ qkv)          // [M][1536]
{
  __shared__ u16 lds[65536];        // 128 KiB
  u16* ldsA = lds;
  u16* ldsB = lds + 32768;

  const int tid = threadIdx.x;
  const int lane = tid & 63, wid = tid >> 6;
  const int wr = wid >> 2, wc = wid & 3;
  const int g4 = lane >> 4, l15 = lane & 15;
  const int xr8 = (g4 ^ ((l15 >> 1) & 3)) * 8;

  const int cpx = gridDim.x >> 3;
  const int logical = (blockIdx.x & 7) * cpx + (blockIdx.x >> 3);
  const int m0 = (logical / 6) * 256;
  const int n0 = (logical % 6) * 256;

  const u16* ga = xbf + (size_t)m0 * E_;
  const u16* gb = wqkv + (size_t)n0 * E_;

  const int r0 = tid >> 2;
  const int c0 = ((tid & 3) ^ ((tid >> 3) & 3)) * 8;

  auto stageA = [&](int e, int h, int kt) {
    const int kc = kt * 64 + h * 32;
    u16* base = ldsA + (e * 2 + h) * 8192;
    gl_lds16(ga + (size_t)r0 * E_ + kc + c0, base + wid * 512);
    gl_lds16(ga + (size_t)(r0 + 128) * E_ + kc + c0, base + 4096 + wid * 512);
  };
  auto stageB = [&](int e, int h, int kt) {
    const int kc = kt * 64 + h * 32;
    u16* base = ldsB + (e * 2 + h) * 8192;
    gl_lds16(gb + (size_t)r0 * E_ + kc + c0, base + wid * 512);
    gl_lds16(gb + (size_t)(r0 + 128) * E_ + kc + c0, base + 4096 + wid * 512);
  };

  f32x4 acc[8][4];
#pragma unroll
  for (int i = 0; i < 8; i++)
#pragma unroll
    for (int j = 0; j < 4; j++) { f32x4 z = {0.f, 0.f, 0.f, 0.f}; acc[i][j] = z; }

  GP_KLOOP()

  // epilogue: + bias, store bf16 token-major, ni innermost (full-line writes)
  float bias4[4];
#pragma unroll
  for (int ni = 0; ni < 4; ni++) {
    const int fcol = n0 + wc * 64 + ni * 16 + l15;
    bias4[ni] = fcol < 512 ? bq[fcol] : (fcol < 1024 ? bk[fcol - 512] : bv[fcol - 1024]);
  }
  const int fbase = n0 + wc * 64 + l15;
#pragma unroll
  for (int mi = 0; mi < 8; mi++)
#pragma unroll
    for (int r = 0; r < 4; r++) {
      const size_t row = m0 + wr * 128 + mi * 16 + g4 * 4 + r;
      u16* dst = qkv + row * NF + fbase;
#pragma unroll
      for (int ni = 0; ni < 4; ni++)
        dst[ni * 16] = f2bf(acc[mi][ni][r] + bias4[ni]);
    }
}

// ---------------- K2: per-(b,p,h) causal attention over T=64, D=64 ----------
__global__ __launch_bounds__(256) void k2_attn(
    const u16* __restrict__ qkv,   // [nb*MCH][1536], token n = b*MCH + t*P_ + p
    u16* __restrict__ o)           // [nb*MCH][512]
{
  __shared__ u16 Pl[4][64 * 72];
  const int tid = threadIdx.x, lane = tid & 63, wid = tid >> 6;
  const int gw = blockIdx.x * 4 + wid;
  const int b = gw >> 11;
  const int g = gw & 2047;
  const int h = g & 7, p = g >> 3;
  const int g4 = lane >> 4;
  const size_t ts = (size_t)P_ * NF;
  const u16* qb = qkv + (size_t)b * MCH * NF + (size_t)p * NF + h * D_;
  const u16* kb = qb + 512;
  const u16* vb = qb + 1024;
  u16* ob = o + (size_t)b * MCH * E_;

  bf16x8 qf[4][2], kf[4][2];
#pragma unroll
  for (int i = 0; i < 4; i++)
#pragma unroll
    for (int ks = 0; ks < 2; ks++) {
      const int rr = i * 16 + (lane & 15);
      const int dc = ks * 32 + g4 * 8;
      qf[i][ks] = ld8(qb + (size_t)rr * ts + dc);
      kf[i][ks] = ld8(kb + (size_t)rr * ts + dc);
    }
  f32x4 S[4][4];
#pragma unroll
  for (int i = 0; i < 4; i++)
#pragma unroll
    for (int j = 0; j < 4; j++) { f32x4 z = {0.f, 0.f, 0.f, 0.f}; S[i][j] = z; }
#pragma unroll
  for (int ks = 0; ks < 2; ks++)
#pragma unroll
    for (int mi = 0; mi < 4; mi++)
#pragma unroll
      for (int ni = 0; ni < 4; ni++)
        S[mi][ni] = mfma16(qf[mi][ks], kf[ni][ks], S[mi][ni]);

  u16* pw = &Pl[wid][0];
#pragma unroll
  for (int mi = 0; mi < 4; mi++)
#pragma unroll
    for (int r = 0; r < 4; r++) {
      const int t = mi * 16 + g4 * 4 + r;
      float v[4]; float mx = -1e30f;
#pragma unroll
      for (int ni = 0; ni < 4; ni++) {
        const int s = ni * 16 + (lane & 15);
        v[ni] = (s <= t) ? S[mi][ni][r] * 0.125f : -1e30f;
        mx = fmaxf(mx, v[ni]);
      }
      mx = fmaxf(mx, __shfl_xor(mx, 1));
      mx = fmaxf(mx, __shfl_xor(mx, 2));
      mx = fmaxf(mx, __shfl_xor(mx, 4));
      mx = fmaxf(mx, __shfl_xor(mx, 8));
      float sum = 0.f; float pv[4];
#pragma unroll
      for (int ni = 0; ni < 4; ni++) {
        const int s = ni * 16 + (lane & 15);
        pv[ni] = (s <= t) ? __expf(v[ni] - mx) : 0.f;
        sum += pv[ni];
      }
      sum += __shfl_xor(sum, 1);
      sum += __shfl_xor(sum, 2);
      sum += __shfl_xor(sum, 4);
      sum += __shfl_xor(sum, 8);
      const float inv = 1.0f / sum;
#pragma unroll
      for (int ni = 0; ni < 4; ni++) {
        const int s = ni * 16 + (lane & 15);
        pw[t * 72 + s] = f2bf(pv[ni] * inv);
      }
    }
  __syncthreads();

  f32x4 O[4][4];
#pragma unroll
  for (int i = 0; i < 4; i++)
#pragma unroll
    for (int j = 0; j < 4; j++) { f32x4 z = {0.f, 0.f, 0.f, 0.f}; O[i][j] = z; }
#pragma unroll
  for (int ks = 0; ks < 2; ks++) {
    bf16x8 pa[4], vf[4];
#pragma unroll
    for (int mi = 0; mi < 4; mi++)
      pa[mi] = ld8(pw + (mi * 16 + (lane & 15)) * 72 + ks * 32 + g4 * 8);
#pragma unroll
    for (int ni = 0; ni < 4; ni++) {
      union { u16 u[8]; bf16x8 b; } tv;
#pragma unroll
      for (int j = 0; j < 8; j++) {
        const int s = ks * 32 + g4 * 8 + j;
        tv.u[j] = vb[(size_t)s * ts + ni * 16 + (lane & 15)];
      }
      vf[ni] = tv.b;
    }
#pragma unroll
    for (int mi = 0; mi < 4; mi++)
#pragma unroll
      for (int ni = 0; ni < 4; ni++)
        O[mi][ni] = mfma16(pa[mi], vf[ni], O[mi][ni]);
  }
#pragma unroll
  for (int mi = 0; mi < 4; mi++)
#pragma unroll
    for (int ni = 0; ni < 4; ni++)
#pragma unroll
      for (int r = 0; r < 4; r++) {
        const int t = mi * 16 + g4 * 4 + r;
        const int d = ni * 16 + (lane & 15);
        ob[((size_t)t * P_ + p) * E_ + h * D_ + d] = f2bf(O[mi][ni][r]);
      }
}

// ---------------- K3a: y = o @ Wo^T + bo + x  (bf16 out) --------------------
// Verbatim k1 pipeline at N=512: 256x256 tile, 2 n-tiles, epilogue adds
// f32 residual and stores bf16 y for the separate LN pass.
__global__ __launch_bounds__(512, 2) void k3_gemm(
    const u16* __restrict__ obf,   // [M][512]
    const u16* __restrict__ wo,    // [512][512]
    const float* __restrict__ bo,
    const float* __restrict__ x,   // [M][512] f32
    u16* __restrict__ yb)          // [M][512] bf16
{
  __shared__ u16 lds[65536];
  u16* ldsA = lds;
  u16* ldsB = lds + 32768;

  const int tid = threadIdx.x;
  const int lane = tid & 63, wid = tid >> 6;
  const int wr = wid >> 2, wc = wid & 3;
  const int g4 = lane >> 4, l15 = lane & 15;
  const int xr8 = (g4 ^ ((l15 >> 1) & 3)) * 8;

  const int cpx = gridDim.x >> 3;
  const int logical = (blockIdx.x & 7) * cpx + (blockIdx.x >> 3);
  const int m0 = (logical >> 1) * 256;
  const int n0 = (logical & 1) * 256;

  const u16* ga = obf + (size_t)m0 * E_;
  const u16* gb = wo + (size_t)n0 * E_;

  const int r0 = tid >> 2;
  const int c0 = ((tid & 3) ^ ((tid >> 3) & 3)) * 8;

  auto stageA = [&](int e, int h, int kt) {
    const int kc = kt * 64 + h * 32;
    u16* base = ldsA + (e * 2 + h) * 8192;
    gl_lds16(ga + (size_t)r0 * E_ + kc + c0, base + wid * 512);
    gl_lds16(ga + (size_t)(r0 + 128) * E_ + kc + c0, base + 4096 + wid * 512);
  };
  auto stageB = [&](int e, int h, int kt) {
    const int kc = kt * 64 + h * 32;
    u16* base = ldsB + (e * 2 + h) * 8192;
    gl_lds16(gb + (size_t)r0 * E_ + kc + c0, base + wid * 512);
    gl_lds16(gb + (size_t)(r0 + 128) * E_ + kc + c0, base + 4096 + wid * 512);
  };

  f32x4 acc[8][4];
#pragma unroll
  for (int i = 0; i < 8; i++)
#pragma unroll
    for (int j = 0; j < 4; j++) { f32x4 z = {0.f, 0.f, 0.f, 0.f}; acc[i][j] = z; }

  GP_KLOOP()

  // epilogue: + bo + x (f32), store bf16, ni innermost
  float bias4[4];
#pragma unroll
  for (int ni = 0; ni < 4; ni++)
    bias4[ni] = bo[n0 + wc * 64 + ni * 16 + l15];
  const int fbase = n0 + wc * 64 + l15;
#pragma unroll
  for (int mi = 0; mi < 8; mi++)
#pragma unroll
    for (int r = 0; r < 4; r++) {
      const size_t row = m0 + wr * 128 + mi * 16 + g4 * 4 + r;
      u16* dst = yb + row * E_ + fbase;
      const float* xr = x + row * E_ + fbase;
#pragma unroll
      for (int ni = 0; ni < 4; ni++)
        dst[ni * 16] = f2bf(acc[mi][ni][r] + bias4[ni] + xr[ni * 16]);
    }
}

// ---------------- K3b: out = LN(y) -----------------------------------------
// Wave per row: lane loads 8 bf16 (16B), 64-lane shfl reduce, float4 stores.
__global__ __launch_bounds__(256) void k3_ln(
    const u16* __restrict__ yb, const float* __restrict__ lng,
    const float* __restrict__ lnb, float* __restrict__ out)
{
  const int lane = threadIdx.x & 63;
  const size_t row = (size_t)blockIdx.x * 4 + (threadIdx.x >> 6);
  const int c = lane * 8;
  const uint4 d = *reinterpret_cast<const uint4*>(yb + row * E_ + c);
  const uint32_t* dw = reinterpret_cast<const uint32_t*>(&d);
  float f[8];
#pragma unroll
  for (int j = 0; j < 4; j++) {
    union { uint32_t u; float v; } lo, hi;
    lo.u = dw[j] << 16; hi.u = dw[j] & 0xffff0000u;
    f[2 * j] = lo.v; f[2 * j + 1] = hi.v;
  }
  float s = 0.f, q = 0.f;
#pragma unroll
  for (int j = 0; j < 8; j++) { s += f[j]; q += f[j] * f[j]; }
#pragma unroll
  for (int d2 = 1; d2 < 64; d2 <<= 1) { s += __shfl_xor(s, d2); q += __shfl_xor(q, d2); }
  const float mean = s * (1.0f / 512.0f);
  const float var = q * (1.0f / 512.0f) - mean * mean;
  const float rs = rsqrtf(var + 1e-5f);
  float o8[8];
#pragma unroll
  for (int j = 0; j < 8; j++)
    o8[j] = (f[j] - mean) * rs * lng[c + j] + lnb[c + j];
  float4* op = reinterpret_cast<float4*>(out + row * E_ + c);
  op[0] = make_float4(o8[0], o8[1], o8[2], o8[3]);
  op[1] = make_float4(o8[4], o8[5], o8[6], o8[7]);
}

extern "C" void kernel_launch(void* const* d_in, const int* in_sizes, int n_in,
                              void* d_out, int out_size, void* d_ws, size_t ws_size,
                              hipStream_t stream) {
  const float* x   = (const float*)d_in[0];
  const float* Wq  = (const float*)d_in[1];
  const float* bq  = (const float*)d_in[2];
  const float* Wk  = (const float*)d_in[3];
  const float* bk  = (const float*)d_in[4];
  const float* Wv  = (const float*)d_in[5];
  const float* bv  = (const float*)d_in[6];
  const float* Wo  = (const float*)d_in[7];
  const float* bo  = (const float*)d_in[8];
  const float* lng = (const float*)d_in[9];
  const float* lnb = (const float*)d_in[10];
  float* out = (float*)d_out;
  uint8_t* ws = (uint8_t*)d_ws;

  const size_t NEED_BIG = 270532608ULL;
  if (ws_size >= NEED_BIG) {
    u16* wqkv = (u16*)(ws);
    u16* wobf = (u16*)(ws + 1572864);
    u16* xbf  = (u16*)(ws + 2097152);         // 64 MiB ; obf aliases after k1
    u16* qkvc = (u16*)(ws + 69206016);        // 192 MiB ; yb aliases after k2
    u16* obf  = xbf;                           // xbf dead after k1
    u16* yb   = qkvc;                          // qkvc dead after k2

    cvt_w<<<512, 256, 0, stream>>>(Wq, Wk, Wv, Wo, wqkv, wobf);
    cvt_bf16<<<16384, 256, 0, stream>>>(x, xbf, B_ * MCH * E_ / 8);
    k1_qkv<<<1536, 512, 0, stream>>>(xbf, wqkv, bq, bk, bv, qkvc);   // 256m x 6n
    k2_attn<<<2048, 256, 0, stream>>>(qkvc, obf);
    k3_gemm<<<512, 512, 0, stream>>>(obf, wobf, bo, x, yb);          // 256m x 2n
    k3_ln<<<16384, 256, 0, stream>>>(yb, lng, lnb, out);
  } else {
    u16* xbf  = (u16*)(ws);                   // 16 MiB
    u16* qkvc = (u16*)(ws + 16777216);        // 48 MiB ; yb aliases after k2
    u16* obf  = (u16*)(ws + 67108864);        // 16 MiB
    u16* wqkv = (u16*)(ws + 83886080);
    u16* wobf = (u16*)(ws + 85458944);
    u16* yb   = qkvc;

    cvt_w<<<512, 256, 0, stream>>>(Wq, Wk, Wv, Wo, wqkv, wobf);
    for (int b = 0; b < B_; ++b) {
      const float* xb = x + (size_t)b * MCH * E_;
      cvt_bf16<<<4096, 256, 0, stream>>>(xb, xbf, MCH * E_ / 8);
      k1_qkv<<<384, 512, 0, stream>>>(xbf, wqkv, bq, bk, bv, qkvc);  // 64m x 6n
      k2_attn<<<512, 256, 0, stream>>>(qkvc, obf);
      k3_gemm<<<128, 512, 0, stream>>>(obf, wobf, bo, xb, yb);       // 64m x 2n
      k3_ln<<<4096, 256, 0, stream>>>(yb, lng, lnb, out + (size_t)b * MCH * E_);
    }
  }
}